// Round 1
// baseline (232.676 us; speedup 1.0000x reference)
//
#include <hip/hip_runtime.h>

#define SC 256   // coarse samples per ray
#define NF 128   // fine (importance) samples per ray

// --- wave (64-lane) primitives ---
__device__ __forceinline__ float wave_incl_scan(float v, int lane) {
    #pragma unroll
    for (int off = 1; off < 64; off <<= 1) {
        float t = __shfl_up(v, off, 64);
        if (lane >= off) v += t;
    }
    return v;
}

__device__ __forceinline__ float wave_sum(float v) {
    #pragma unroll
    for (int off = 32; off; off >>= 1) v += __shfl_xor(v, off, 64);
    return v;
}

__global__ __launch_bounds__(256) void nerf_render_kernel(
    const float* __restrict__ sig_c,   // [N, 256]
    const float* __restrict__ sig_f,   // [N, 128]
    const float* __restrict__ rgb_f,   // [N, 128, 3]
    const float* __restrict__ bg,      // [3]
    float* __restrict__ out,           // image|invdepth|w_fine|z_log_s concat
    int n_rays)
{
    const int lane = threadIdx.x & 63;
    const int wid  = threadIdx.x >> 6;          // wave (= ray) within block
    const int ray  = (blockIdx.x << 2) + wid;
    if (ray >= n_rays) return;

    __shared__ float s_cdf[4][SC];

    // ---------------- coarse pass: weights on uniform log grid ----------------
    // z_log[j] = -2 + j/64 exactly; delta = 1/64 except last (=0)
    const float4 sc4 = *reinterpret_cast<const float4*>(sig_c + (size_t)ray * SC + 4 * lane);
    const float DLT = 0.015625f;
    float x0 = sc4.x * DLT;
    float x1 = sc4.y * DLT;
    float x2 = sc4.z * DLT;
    float x3 = (lane == 63) ? 0.0f : sc4.w * DLT;   // last delta = 0

    float p0 = x0, p1 = p0 + x1, p2 = p1 + x2, p3 = p2 + x3;
    float incl = wave_incl_scan(p3, lane);
    float excl = incl - p3;                          // cum before this lane's 1st sample

    // transmittance at sample boundaries; w_j = T_j - T_{j+1}
    float T0 = expf(-excl);
    float T1 = expf(-(excl + p0));
    float T2 = expf(-(excl + p1));
    float T3 = expf(-(excl + p2));
    float T4 = expf(-(excl + p3));
    float w0 = T0 - T1, w1 = T1 - T2, w2 = T2 - T3, w3 = T3 - T4;

    // ---------------- reweight: 3-tap max blur + floor (seg scale cancels) ----
    float wl = __shfl_up(w3, 1, 64);  if (lane == 0)  wl = 0.0f;
    float wr = __shfl_down(w0, 1, 64); if (lane == 63) wr = 0.0f;

    const float FLOOR = 0.01f / 256.0f;
    float m01 = fmaxf(w0, w1), m12 = fmaxf(w1, w2), m23 = fmaxf(w2, w3);
    float r0 = 0.5f * (fmaxf(wl, w0) + m01) + FLOOR;
    float r1 = 0.5f * (m01 + m12) + FLOOR;
    float r2 = 0.5f * (m12 + m23) + FLOOR;
    float r3 = 0.5f * (m23 + fmaxf(w3, wr)) + FLOOR;

    // ---------------- normalized CDF into LDS ----------------
    float q0 = r0, q1 = q0 + r1, q2 = q1 + r2, q3 = q2 + r3;
    float incl2 = wave_incl_scan(q3, lane);
    float excl2 = incl2 - q3;
    float total = __shfl(incl2, 63, 64);
    float inv_total = 1.0f / total;

    *reinterpret_cast<float4*>(&s_cdf[wid][4 * lane]) = make_float4(
        (excl2 + q0) * inv_total, (excl2 + q1) * inv_total,
        (excl2 + q2) * inv_total, (excl2 + q3) * inv_total);

    __syncthreads();

    // ---------------- inverse-CDF sampling (searchsorted right + lerp) --------
    const float* cdf = s_cdf[wid];
    float zl[2];
    #pragma unroll
    for (int s = 0; s < 2; ++s) {
        const int k = 2 * lane + s;
        const float u = ((float)k + 0.5f) * (1.0f / 128.0f);
        // pos = count of cdf entries <= u  (searchsorted side='right')
        int pos = 0;
        #pragma unroll
        for (int step = 128; step >= 1; step >>= 1) {
            if (cdf[pos + step - 1] <= u) pos += step;   // max idx touched = 254
        }
        int below = pos - 1; if (below < 0) below = 0;
        int above = pos;     if (above > SC - 1) above = SC - 1;
        float cdf_b = cdf[below];
        float cdf_a = cdf[above];
        float bin_b = -2.0f + (float)below * 0.015625f;
        float bin_a = -2.0f + (float)above * 0.015625f;
        float dn = cdf_a - cdf_b;
        dn = (dn < 1e-5f) ? 1.0f : dn;
        float t = (u - cdf_b) / dn;
        zl[s] = bin_b + t * (bin_a - bin_b);
    }
    float zl0 = zl[0], zl1 = zl[1];

    // ---------------- fine pass: weights on sampled grid ----------------
    float znext = __shfl_down(zl0, 1, 64);          // next lane's first z
    float d0 = zl1 - zl0;
    float d1 = (lane == 63) ? 0.0f : (znext - zl1); // last delta = 0

    const float2 sf = *reinterpret_cast<const float2*>(sig_f + (size_t)ray * NF + 2 * lane);
    float y0 = sf.x * d0;
    float y1 = sf.y * d1;
    float ps = y0 + y1;
    float fincl = wave_incl_scan(ps, lane);
    float fexcl = fincl - ps;

    float U0 = expf(-fexcl);
    float U1 = expf(-(fexcl + y0));
    float U2 = expf(-(fexcl + ps));
    float wf0 = U0 - U1, wf1 = U1 - U2;

    // ---------------- compositing ----------------
    const float2* rp = reinterpret_cast<const float2*>(rgb_f + (size_t)ray * (NF * 3) + 6 * lane);
    float2 ra = rp[0], rb = rp[1], rc = rp[2];
    // sample 2l rgb = (ra.x, ra.y, rb.x); sample 2l+1 rgb = (rb.y, rc.x, rc.y)
    float img_r = wf0 * ra.x + wf1 * rb.y;
    float img_g = wf0 * ra.y + wf1 * rc.x;
    float img_b = wf0 * rb.x + wf1 * rc.y;
    float wsum  = wf0 + wf1;
    float z0 = exp10f(zl0), z1 = exp10f(zl1);
    float invd = wf0 / z0 + wf1 / z1;

    img_r = wave_sum(img_r);
    img_g = wave_sum(img_g);
    img_b = wave_sum(img_b);
    wsum  = wave_sum(wsum);
    invd  = wave_sum(invd);

    // ---------------- outputs ----------------
    float* out_img  = out;
    float* out_invd = out + (size_t)n_rays * 3;
    float* out_wf   = out + (size_t)n_rays * 4;
    float* out_zs   = out + (size_t)n_rays * 4 + (size_t)n_rays * NF;

    if (lane == 0) {
        float one_m = 1.0f - wsum;
        out_img[(size_t)ray * 3 + 0] = img_r + one_m * bg[0];
        out_img[(size_t)ray * 3 + 1] = img_g + one_m * bg[1];
        out_img[(size_t)ray * 3 + 2] = img_b + one_m * bg[2];
        out_invd[ray] = invd;
    }
    *reinterpret_cast<float2*>(out_wf + (size_t)ray * NF + 2 * lane) =
        make_float2(wf0, wf1);
    *reinterpret_cast<float2*>(out_zs + (size_t)ray * NF + 2 * lane) =
        make_float2((zl0 + 2.0f) * 0.25f, (zl1 + 2.0f) * 0.25f);
}

extern "C" void kernel_launch(void* const* d_in, const int* in_sizes, int n_in,
                              void* d_out, int out_size, void* d_ws, size_t ws_size,
                              hipStream_t stream) {
    const float* sig_c = (const float*)d_in[0];
    const float* sig_f = (const float*)d_in[1];
    const float* rgb_f = (const float*)d_in[2];
    const float* bg    = (const float*)d_in[3];
    float* out = (float*)d_out;

    const int n_rays = in_sizes[1] / NF;   // 65536
    dim3 grid((n_rays + 3) / 4), block(256);
    hipLaunchKernelGGL(nerf_render_kernel, grid, block, 0, stream,
                       sig_c, sig_f, rgb_f, bg, out, n_rays);
}

// Round 2
// 232.585 us; speedup vs baseline: 1.0004x; 1.0004x over previous
//
#include <hip/hip_runtime.h>

#define SC 256   // coarse samples per ray
#define NF 128   // fine (importance) samples per ray

// ---------- DPP helpers (VALU cross-lane; avoids ds_bpermute LDS-pipe ops) ----------
template<int CTRL, int RM, int BM>
__device__ __forceinline__ float dpp_add(float x) {
    int s = __builtin_amdgcn_update_dpp(0, __float_as_int(x), CTRL, RM, BM, true);
    return x + __int_as_float(s);
}
template<int CTRL>
__device__ __forceinline__ float dpp_mov0(float x) {   // zero-fill out-of-range lanes
    return __int_as_float(__builtin_amdgcn_update_dpp(0, __float_as_int(x), CTRL, 0xF, 0xF, true));
}
__device__ __forceinline__ float lane_f(float x, int l) {
    return __int_as_float(__builtin_amdgcn_readlane(__float_as_int(x), l));
}

// wave64 inclusive scan: 6 DPP adds (classic GCN sequence), no LDS traffic
__device__ __forceinline__ float wave_incl_scan(float x) {
    x = dpp_add<0x111, 0xF, 0xF>(x);   // row_shr:1
    x = dpp_add<0x112, 0xF, 0xF>(x);   // row_shr:2
    x = dpp_add<0x114, 0xF, 0xF>(x);   // row_shr:4
    x = dpp_add<0x118, 0xF, 0xF>(x);   // row_shr:8
    x = dpp_add<0x142, 0xA, 0xF>(x);   // row_bcast:15 -> rows 1,3
    x = dpp_add<0x143, 0xC, 0xF>(x);   // row_bcast:31 -> rows 2,3
    return x;
}

// reduction valid on lane 0: 4 DPP adds + 3 readlane + 3 adds (zero LDS-pipe)
__device__ __forceinline__ float wave_sum_lane0(float x) {
    x = dpp_add<0xB1, 0xF, 0xF>(x);    // quad_perm(1,0,3,2)  xor1
    x = dpp_add<0x4E, 0xF, 0xF>(x);    // quad_perm(2,3,0,1)  xor2
    x = dpp_add<0x124, 0xF, 0xF>(x);   // row_ror:4
    x = dpp_add<0x128, 0xF, 0xF>(x);   // row_ror:8  -> each lane holds its row-of-16 sum
    return x + lane_f(x, 16) + lane_f(x, 32) + lane_f(x, 48);
}

__global__ __launch_bounds__(256) void nerf_render_kernel(
    const float* __restrict__ sig_c,   // [N, 256]
    const float* __restrict__ sig_f,   // [N, 128]
    const float* __restrict__ rgb_f,   // [N, 128, 3]
    const float* __restrict__ bg,      // [3]
    float* __restrict__ out,           // image|invdepth|w_fine|z_log_s concat
    int n_rays)
{
    const int lane = threadIdx.x & 63;
    const int wid  = threadIdx.x >> 6;          // wave (= ray) within block
    const int ray  = (blockIdx.x << 2) + wid;
    if (ray >= n_rays) return;

    __shared__ float s_cdf[4][SC];

    // ---------------- coarse pass: weights on uniform log grid ----------------
    // z_log[j] = -2 + j/64 exactly; delta = 1/64 except last (=0)
    const float4 sc4 = *reinterpret_cast<const float4*>(sig_c + (size_t)ray * SC + 4 * lane);
    const float DLT = 0.015625f;
    float x0 = sc4.x * DLT;
    float x1 = sc4.y * DLT;
    float x2 = sc4.z * DLT;
    float x3 = (lane == 63) ? 0.0f : sc4.w * DLT;   // last delta = 0

    float p0 = x0, p1 = p0 + x1, p2 = p1 + x2, p3 = p2 + x3;
    float incl = wave_incl_scan(p3);
    float excl = incl - p3;                          // cum before this lane's 1st sample

    // transmittance at sample boundaries; w_j = T_j - T_{j+1}
    float T0 = __expf(-excl);
    float T1 = __expf(-(excl + p0));
    float T2 = __expf(-(excl + p1));
    float T3 = __expf(-(excl + p2));
    float T4 = __expf(-(excl + p3));
    float w0 = T0 - T1, w1 = T1 - T2, w2 = T2 - T3, w3 = T3 - T4;

    // ---------------- reweight: 3-tap max blur + floor (seg scale cancels) ----
    float wl = dpp_mov0<0x138>(w3);   // wave_shr:1 : lane i <- lane i-1, lane0 <- 0
    float wr = dpp_mov0<0x130>(w0);   // wave_shl:1 : lane i <- lane i+1, lane63 <- 0

    const float FLOOR = 0.01f / 256.0f;
    float m01 = fmaxf(w0, w1), m12 = fmaxf(w1, w2), m23 = fmaxf(w2, w3);
    float r0 = 0.5f * (fmaxf(wl, w0) + m01) + FLOOR;
    float r1 = 0.5f * (m01 + m12) + FLOOR;
    float r2 = 0.5f * (m12 + m23) + FLOOR;
    float r3 = 0.5f * (m23 + fmaxf(w3, wr)) + FLOOR;

    // ---------------- normalized CDF into LDS ----------------
    float q0 = r0, q1 = q0 + r1, q2 = q1 + r2, q3 = q2 + r3;
    float incl2 = wave_incl_scan(q3);
    float excl2 = incl2 - q3;
    float total = lane_f(incl2, 63);
    float inv_total = __builtin_amdgcn_rcpf(total);

    *reinterpret_cast<float4*>(&s_cdf[wid][4 * lane]) = make_float4(
        (excl2 + q0) * inv_total, (excl2 + q1) * inv_total,
        (excl2 + q2) * inv_total, (excl2 + q3) * inv_total);

    __syncthreads();

    // ---------------- inverse-CDF sampling (searchsorted right + lerp) --------
    const float* cdf = s_cdf[wid];
    float zl[2];
    #pragma unroll
    for (int s = 0; s < 2; ++s) {
        const int k = 2 * lane + s;
        const float u = ((float)k + 0.5f) * (1.0f / 128.0f);
        // pos = count of cdf entries <= u  (searchsorted side='right')
        int pos = 0;
        #pragma unroll
        for (int step = 128; step >= 1; step >>= 1) {
            if (cdf[pos + step - 1] <= u) pos += step;   // max idx touched = 254
        }
        int below = pos - 1; if (below < 0) below = 0;
        int above = pos;     if (above > SC - 1) above = SC - 1;
        float cdf_b = cdf[below];
        float cdf_a = cdf[above];
        float bin_b = -2.0f + (float)below * 0.015625f;
        float bin_a = -2.0f + (float)above * 0.015625f;
        float dn = cdf_a - cdf_b;
        dn = (dn < 1e-5f) ? 1.0f : dn;
        float t = (u - cdf_b) / dn;
        zl[s] = bin_b + t * (bin_a - bin_b);
    }
    float zl0 = zl[0], zl1 = zl[1];

    // ---------------- fine pass: weights on sampled grid ----------------
    float znext = dpp_mov0<0x130>(zl0);             // wave_shl:1 -> next lane's first z
    float d0 = zl1 - zl0;
    float d1 = (lane == 63) ? 0.0f : (znext - zl1); // last delta = 0

    const float2 sf = *reinterpret_cast<const float2*>(sig_f + (size_t)ray * NF + 2 * lane);
    float y0 = sf.x * d0;
    float y1 = sf.y * d1;
    float ps = y0 + y1;
    float fincl = wave_incl_scan(ps);
    float fexcl = fincl - ps;

    float U0 = __expf(-fexcl);
    float U1 = __expf(-(fexcl + y0));
    float U2 = __expf(-(fexcl + ps));
    float wf0 = U0 - U1, wf1 = U1 - U2;

    // ---------------- compositing ----------------
    const float2* rp = reinterpret_cast<const float2*>(rgb_f + (size_t)ray * (NF * 3) + 6 * lane);
    float2 ra = rp[0], rb = rp[1], rc = rp[2];
    // sample 2l rgb = (ra.x, ra.y, rb.x); sample 2l+1 rgb = (rb.y, rc.x, rc.y)
    float img_r = wf0 * ra.x + wf1 * rb.y;
    float img_g = wf0 * ra.y + wf1 * rc.x;
    float img_b = wf0 * rb.x + wf1 * rc.y;
    float wsum  = wf0 + wf1;
    // 1/z = 10^(-z_log): no divide needed
    float invd = wf0 * __exp10f(-zl0) + wf1 * __exp10f(-zl1);

    img_r = wave_sum_lane0(img_r);
    img_g = wave_sum_lane0(img_g);
    img_b = wave_sum_lane0(img_b);
    wsum  = wave_sum_lane0(wsum);
    invd  = wave_sum_lane0(invd);

    // ---------------- outputs ----------------
    float* out_img  = out;
    float* out_invd = out + (size_t)n_rays * 3;
    float* out_wf   = out + (size_t)n_rays * 4;
    float* out_zs   = out + (size_t)n_rays * 4 + (size_t)n_rays * NF;

    if (lane == 0) {
        float one_m = 1.0f - wsum;
        out_img[(size_t)ray * 3 + 0] = img_r + one_m * bg[0];
        out_img[(size_t)ray * 3 + 1] = img_g + one_m * bg[1];
        out_img[(size_t)ray * 3 + 2] = img_b + one_m * bg[2];
        out_invd[ray] = invd;
    }
    *reinterpret_cast<float2*>(out_wf + (size_t)ray * NF + 2 * lane) =
        make_float2(wf0, wf1);
    *reinterpret_cast<float2*>(out_zs + (size_t)ray * NF + 2 * lane) =
        make_float2((zl0 + 2.0f) * 0.25f, (zl1 + 2.0f) * 0.25f);
}

extern "C" void kernel_launch(void* const* d_in, const int* in_sizes, int n_in,
                              void* d_out, int out_size, void* d_ws, size_t ws_size,
                              hipStream_t stream) {
    const float* sig_c = (const float*)d_in[0];
    const float* sig_f = (const float*)d_in[1];
    const float* rgb_f = (const float*)d_in[2];
    const float* bg    = (const float*)d_in[3];
    float* out = (float*)d_out;

    const int n_rays = in_sizes[1] / NF;   // 65536
    dim3 grid((n_rays + 3) / 4), block(256);
    hipLaunchKernelGGL(nerf_render_kernel, grid, block, 0, stream,
                       sig_c, sig_f, rgb_f, bg, out, n_rays);
}